// Round 5
// baseline (753.455 us; speedup 1.0000x reference)
//
#include <hip/hip_runtime.h>

// Screen: 2D histogram of 16,777,216 particles into a 1024x1024 fp32 image.
// Round 12: STRUCTURAL REWRITE — drop the sort pipeline (k1-k4), go direct.
//  R9-R11 ground k3 from 88.8 -> 65.9 us with three scheduling rounds; gains
//  hit zero and k3's phase-barrier structure pins VGPR=32 / latency-bound.
//  Arithmetic: compulsory traffic is 128 MB (xs,ys) ~= 21 us; the hottest
//  pixel gets only ~270 hits (Gaussian sigma=100px), so direct global
//  atomics are issue-bound, not contention-bound, and fire-and-forget
//  global_atomic_add does not stall the wave.
//  Structure: memset 32 MB -> hist8 (read 128 MB, atomicAdd into 8
//  privatized u32 image copies, copy = blockIdx&7 = XCD id under round-robin
//  dispatch -> copy lives in local XCD L2) -> reduce8 (sum 8 copies, convert
//  to f32, write image).
//  Predicted: hist8 ~25-45 us (FETCH ~130 MB, HBM 50-80%, bank-conflict 0),
//  reduce8 ~6-10 us, total 45-70 us. If hist8 >100 us with low HBM%, the
//  atomic path is the wall -> revert to sort pipeline.

#define NXX 1024
#define NYY 1024
#define NPIX (NXX * NYY)
#define NCOPIES 8

// ---- binning constants (match reference; approx-div absorbed by absmax) ----
#define SCR_LEFT   (-0.00512f)
#define SCR_RIGHT  ( 0.00512f)
#define SCR_BOTTOM (-0.00512f)
#define SCR_TOP    ( 0.00512f)
#define SCR_INV    (100000.0f)   // 1/1e-5

// ---------- hist8: grid-stride, 4 particles/iter, privatized atomics ----------
__global__ __launch_bounds__(256) void hist8(
    const float4* __restrict__ xs4, const float4* __restrict__ ys4,
    const float* __restrict__ mis, unsigned int* __restrict__ copies, int n4) {
    const float mx = mis[0], my = mis[1];
    unsigned int* __restrict__ my_copy =
        copies + (size_t)(blockIdx.x & (NCOPIES - 1)) * NPIX;
    const int stride = gridDim.x * blockDim.x;
    for (int i = blockIdx.x * blockDim.x + threadIdx.x; i < n4; i += stride) {
        float4 xv = xs4[i], yv = ys4[i];
        #pragma unroll
        for (int e = 0; e < 4; ++e) {
            float xx = (e == 0 ? xv.x : e == 1 ? xv.y : e == 2 ? xv.z : xv.w) - mx;
            float yy = (e == 0 ? yv.x : e == 1 ? yv.y : e == 2 ? yv.z : yv.w) - my;
            // y-bin (row is flipped: image[NY-1-iy])
            if (!((yy >= SCR_BOTTOM) & (yy <= SCR_TOP))) continue;
            if (!((xx >= SCR_LEFT) & (xx <= SCR_RIGHT))) continue;
            int iy = __float2int_rd((yy - SCR_BOTTOM) * SCR_INV);
            iy = min(max(iy, 0), NYY - 1);
            int ix = __float2int_rd((xx - SCR_LEFT) * SCR_INV);
            ix = min(max(ix, 0), NXX - 1);
            unsigned int r = (unsigned int)((NYY - 1) - iy);
            atomicAdd(&my_copy[r * NXX + (unsigned int)ix], 1u);  // fire-and-forget
        }
    }
}

// ---------- reduce8: sum the 8 copies, convert to f32 ----------
__global__ __launch_bounds__(256) void reduce8(
    const uint4* __restrict__ copies, float4* __restrict__ out) {
    const int idx = blockIdx.x * blockDim.x + threadIdx.x;   // 0 .. NPIX/4-1
    uint4 s = copies[idx];
    #pragma unroll
    for (int c = 1; c < NCOPIES; ++c) {
        uint4 v = copies[(size_t)c * (NPIX / 4) + idx];
        s.x += v.x; s.y += v.y; s.z += v.z; s.w += v.w;
    }
    out[idx] = make_float4((float)s.x, (float)s.y, (float)s.z, (float)s.w);
}

// ---------- Fallback (single-copy, into d_out) if ws too small ----------
__global__ __launch_bounds__(256) void fallback_hist(
    const float4* __restrict__ xs4, const float4* __restrict__ ys4,
    const float* __restrict__ mis, unsigned int* __restrict__ out, int n4) {
    const float mx = mis[0], my = mis[1];
    const int stride = gridDim.x * blockDim.x;
    for (int i = blockIdx.x * blockDim.x + threadIdx.x; i < n4; i += stride) {
        float4 xv = xs4[i], yv = ys4[i];
        #pragma unroll
        for (int e = 0; e < 4; ++e) {
            float xx = (e == 0 ? xv.x : e == 1 ? xv.y : e == 2 ? xv.z : xv.w) - mx;
            float yy = (e == 0 ? yv.x : e == 1 ? yv.y : e == 2 ? yv.z : yv.w) - my;
            if (!((yy >= SCR_BOTTOM) & (yy <= SCR_TOP))) continue;
            if (!((xx >= SCR_LEFT) & (xx <= SCR_RIGHT))) continue;
            int iy = __float2int_rd((yy - SCR_BOTTOM) * SCR_INV);
            iy = min(max(iy, 0), NYY - 1);
            int ix = __float2int_rd((xx - SCR_LEFT) * SCR_INV);
            ix = min(max(ix, 0), NXX - 1);
            unsigned int r = (unsigned int)((NYY - 1) - iy);
            atomicAdd(&out[r * NXX + (unsigned int)ix], 1u);
        }
    }
}
__global__ __launch_bounds__(256) void convert_kernel(unsigned int* __restrict__ buf, int n) {
    int i = blockIdx.x * blockDim.x + threadIdx.x;
    if (i < n) { unsigned int c = buf[i]; ((float*)buf)[i] = (float)c; }
}

extern "C" void kernel_launch(void* const* d_in, const int* in_sizes, int n_in,
                              void* d_out, int out_size, void* d_ws, size_t ws_size,
                              hipStream_t stream) {
    const float* xs  = (const float*)d_in[0];
    const float* ys  = (const float*)d_in[1];
    const float* mis = (const float*)d_in[2];

    const int n  = in_sizes[0];   // 16,777,216
    const int n4 = n / 4;

    const size_t priv_bytes = (size_t)NCOPIES * NPIX * sizeof(unsigned int); // 32 MB

    if (ws_size >= priv_bytes) {
        unsigned int* copies = (unsigned int*)d_ws;
        hipMemsetAsync(copies, 0, priv_bytes, stream);
        hist8<<<2048, 256, 0, stream>>>(
            (const float4*)xs, (const float4*)ys, mis, copies, n4);
        reduce8<<<NPIX / 4 / 256, 256, 0, stream>>>(
            (const uint4*)copies, (float4*)d_out);
        return;
    }

    // ws too small: single-copy atomics directly in d_out, then convert.
    unsigned int* out_u = (unsigned int*)d_out;
    hipMemsetAsync(d_out, 0, (size_t)NPIX * sizeof(float), stream);
    fallback_hist<<<2048, 256, 0, stream>>>(
        (const float4*)xs, (const float4*)ys, mis, out_u, n4);
    convert_kernel<<<(NPIX + 255) / 256, 256, 0, stream>>>(out_u, NPIX);
}

// Round 6
// 225.255 us; speedup vs baseline: 3.3449x; 3.3449x over previous
//
#include <hip/hip_runtime.h>

// Screen: 2D histogram of 16,777,216 particles into a 1024x1024 fp32 image.
// Round 13: revert R12 (direct global atomics: 640us, WRITE_SIZE 523MB --
//  L2 thrash between 128MB input stream and histogram lines; falsifier
//  triggered). Back to sort pipeline, but k3 REORDER DELETED:
//  R9-R11 showed k3 pinned at ~65us by the reorder machinery (78KB LDS,
//  block scan, 16.7M LDS reorder writes+reads, barrier-phased copy loop).
//  The reorder only coalesced the key write; key scatter has row-segment
//  locality (dense, rank-contiguous per block) that L2 aggregates.
//  New k3: count-atomics (rank) -> 1 cursor atomic/row -> direct scattered
//  u16 stores to keys[row*cap + base + rank]. LDS 78KB -> 12KB.
//  Predicted: k3 ~35-48us, WRITE ~50-80MB (falsifier: >150MB -> reorder
//  returns), k4 surfaces as top dispatch (~55-60us), total ~140-155us.

#define NXX 1024
#define NYY 1024
#define NROWS 1024
#define K3_THREADS 1024
#define K3_CHUNK 16384         // particles per K3 block
#define K3_G4 (K3_CHUNK / 4)   // 4096 float4 groups per block
#define HCOPIES 8
#define HSTRIDE 1025

// ---- binning (approx-div; absmax budget absorbs ~2ulp edge misbins) ----
static __device__ __forceinline__ unsigned int row_of(float y) {
    const float BOTTOM = (float)(-1024.0 * 1e-5 / 2.0);
    const float TOP    = (float)( 1024.0 * 1e-5 / 2.0);
    const float INVV   = 1.0f / 1e-5f;
    if (!((y >= BOTTOM) & (y <= TOP))) return 0xFFFFFFFFu;
    int iy = __float2int_rd((y - BOTTOM) * INVV);
    iy = min(max(iy, 0), NYY - 1);
    return (unsigned int)((NYY - 1) - iy);
}

// (row<<16)|col ; col=0xFFFF sentinel when x-invalid (slot reserved, K4 dumps)
// 0xFFFFFFFF = y-invalid, no slot.
static __device__ __forceinline__ unsigned int key_of32(float x, float y) {
    unsigned int r = row_of(y);
    if (r == 0xFFFFFFFFu) return 0xFFFFFFFFu;
    const float LEFT  = (float)(-1024.0 * 1e-5 / 2.0);
    const float RIGHT = (float)( 1024.0 * 1e-5 / 2.0);
    const float INVH  = 1.0f / 1e-5f;
    unsigned int col;
    if ((x >= LEFT) & (x <= RIGHT)) {
        int ix = __float2int_rd((x - LEFT) * INVH);
        col = (unsigned int)min(max(ix, 0), NXX - 1);
    } else {
        col = 0xFFFFu;
    }
    return (r << 16) | col;
}

// ---------- K3: row-binned direct scatter of u16 column keys ----------
// cursors hold DELTAS (zeroed by memset); global base = row*cap + delta.
__global__ __launch_bounds__(K3_THREADS) void k3_scatter(
    const float4* __restrict__ xs4, const float4* __restrict__ ys4,
    const float* __restrict__ mis, unsigned int* __restrict__ cursors,
    unsigned short* __restrict__ keys, unsigned int cap) {
    __shared__ unsigned int lCount[NROWS];   // per-row count (this block)
    __shared__ unsigned int lBase[NROWS];    // row*cap + cursor delta base
    __shared__ unsigned int lLim[NROWS];     // remaining capacity for this block

    const int t = threadIdx.x;
    lCount[t] = 0u;
    __syncthreads();
    const float mx = mis[0], my = mis[1];

    const int base4 = blockIdx.x * K3_G4;

    // phase A1: prefetch all 8 vectors (8 global_load_dwordx4 in flight),
    // then compute all 16 keys (pure VALU).
    float4 xv[4], yv[4];
    #pragma unroll
    for (int j = 0; j < 4; ++j) xv[j] = xs4[base4 + j * K3_THREADS + t];
    #pragma unroll
    for (int j = 0; j < 4; ++j) yv[j] = ys4[base4 + j * K3_THREADS + t];

    unsigned int mykey[16];
    #pragma unroll
    for (int j = 0; j < 4; ++j) {
        #pragma unroll
        for (int e = 0; e < 4; ++e) {
            float xx = (e == 0 ? xv[j].x : e == 1 ? xv[j].y : e == 2 ? xv[j].z : xv[j].w) - mx;
            float yy = (e == 0 ? yv[j].x : e == 1 ? yv[j].y : e == 2 ? yv[j].z : yv[j].w) - my;
            mykey[j * 4 + e] = key_of32(xx, yy);
        }
    }

    // phase A2: batched counting atomics -> within-(block,row) rank.
    unsigned short myrank[16];
    #pragma unroll
    for (int j = 0; j < 16; ++j) {
        unsigned int k = mykey[j];
        unsigned int rk = 0;
        if (k != 0xFFFFFFFFu) rk = atomicAdd(&lCount[k >> 16], 1u);
        myrank[j] = (unsigned short)rk;
    }
    __syncthreads();

    // phase B: one global cursor atomic per non-empty row (thread t = row t).
    unsigned int c = lCount[t];
    unsigned int b = 0u;
    if (c) b = atomicAdd(&cursors[t], c);
    lBase[t] = (unsigned int)t * cap + b;
    lLim[t]  = (b < cap) ? (cap - b) : 0u;   // overflow guard (cap sized so never hit)
    __syncthreads();

    // phase C: direct scattered u16 stores (fire-and-forget; L2 aggregates
    // rank-contiguous row segments).
    #pragma unroll
    for (int j = 0; j < 16; ++j) {
        unsigned int k = mykey[j];
        if (k != 0xFFFFFFFFu) {
            unsigned int row = k >> 16;
            unsigned int rk = myrank[j];
            if (rk < lLim[row])
                keys[lBase[row] + rk] = (unsigned short)k;
        }
    }
}

// ---------- K4: per-row replicated LDS histogram -> image row ----------
// start = r*cap, cnt = delta[r] (clamped to cap).
__global__ __launch_bounds__(1024) void k4_hist(
    const unsigned short* __restrict__ keys,
    const unsigned int* __restrict__ cnts,
    float* __restrict__ out, unsigned int cap) {
    __shared__ unsigned int hist[HCOPIES * HSTRIDE];
    const int b = blockIdx.x;
    const int r = (b & 1) ? (512 + (b >> 1)) : (511 - (b >> 1));  // center-first
    for (int t = threadIdx.x; t < HCOPIES * HSTRIDE; t += 1024) hist[t] = 0u;
    __syncthreads();
    unsigned int start = (unsigned int)r * cap;
    unsigned int cnt = cnts[r];
    if (cnt > cap) cnt = cap;
    const unsigned int copy = (threadIdx.x & (HCOPIES - 1)) * HSTRIDE;
    // dump slot: sentinel cols (0xFFFF) -> hist[copy + 1024] (never reduced)
    unsigned int head = (8u - (start & 7u)) & 7u;   // align to 16 B
    if (head > cnt) head = cnt;
    if (threadIdx.x < head) {
        unsigned int c = min((unsigned int)keys[start + threadIdx.x], 1024u);
        atomicAdd(&hist[copy + c], 1u);
    }
    const unsigned int m = cnt - head;
    const uint4* pk = (const uint4*)(keys + start + head);
    const unsigned int octs = m >> 3;
    for (unsigned int q = threadIdx.x; q < octs; q += 1024) {
        uint4 v = pk[q];
        atomicAdd(&hist[copy + min(v.x & 0xFFFFu, 1024u)], 1u);
        atomicAdd(&hist[copy + min(v.x >> 16,     1024u)], 1u);
        atomicAdd(&hist[copy + min(v.y & 0xFFFFu, 1024u)], 1u);
        atomicAdd(&hist[copy + min(v.y >> 16,     1024u)], 1u);
        atomicAdd(&hist[copy + min(v.z & 0xFFFFu, 1024u)], 1u);
        atomicAdd(&hist[copy + min(v.z >> 16,     1024u)], 1u);
        atomicAdd(&hist[copy + min(v.w & 0xFFFFu, 1024u)], 1u);
        atomicAdd(&hist[copy + min(v.w >> 16,     1024u)], 1u);
    }
    const unsigned int tail = m & 7u;
    if (threadIdx.x < tail) {
        unsigned int c = min((unsigned int)keys[start + head + (octs << 3) + threadIdx.x], 1024u);
        atomicAdd(&hist[copy + c], 1u);
    }
    __syncthreads();
    float* dst = out + (size_t)r * NXX;
    for (int v = threadIdx.x; v < NXX; v += 1024) {
        unsigned int s = 0u;
        #pragma unroll
        for (int c2 = 0; c2 < HCOPIES; ++c2) s += hist[c2 * HSTRIDE + v];
        dst[v] = (float)s;
    }
}

// ---------- Fallback (global-atomic path) if ws too small ----------
__global__ __launch_bounds__(256) void fallback_hist(
    const float4* __restrict__ xs4, const float4* __restrict__ ys4,
    const float* __restrict__ mis, unsigned int* __restrict__ out, int n4) {
    const float mx = mis[0], my = mis[1];
    const int stride = gridDim.x * blockDim.x;
    for (int i = blockIdx.x * blockDim.x + threadIdx.x; i < n4; i += stride) {
        float4 xv = xs4[i], yv = ys4[i];
        #pragma unroll
        for (int e = 0; e < 4; ++e) {
            float xx = (e == 0 ? xv.x : e == 1 ? xv.y : e == 2 ? xv.z : xv.w) - mx;
            float yy = (e == 0 ? yv.x : e == 1 ? yv.y : e == 2 ? yv.z : yv.w) - my;
            unsigned int k = key_of32(xx, yy);
            if (k != 0xFFFFFFFFu && (k & 0xFFFFu) < NXX)
                atomicAdd(&out[(k >> 16) * NXX + (k & 0xFFFFu)], 1u);
        }
    }
}
__global__ __launch_bounds__(256) void convert_kernel(unsigned int* __restrict__ buf, int n) {
    int i = blockIdx.x * blockDim.x + threadIdx.x;
    if (i < n) { unsigned int c = buf[i]; ((float*)buf)[i] = (float)c; }
}

extern "C" void kernel_launch(void* const* d_in, const int* in_sizes, int n_in,
                              void* d_out, int out_size, void* d_ws, size_t ws_size,
                              hipStream_t stream) {
    const float* xs  = (const float*)d_in[0];
    const float* ys  = (const float*)d_in[1];
    const float* mis = (const float*)d_in[2];

    const int n  = in_sizes[0];   // 16,777,216
    const int n4 = n / 4;

    unsigned char* ws = (unsigned char*)d_ws;
    unsigned int* cursors32 = (unsigned int*)(ws);          // delta[row], 1024 u32
    unsigned short* keys    = (unsigned short*)(ws + 65536);

    // Capacity path sizing: peak row ~67K keys; need cap >= 72K margin.
    unsigned int cap = 0;
    if (ws_size > 65536) {
        size_t c = (ws_size - 65536) / (NROWS * sizeof(unsigned short));
        c &= ~(size_t)63;
        if (c >= 73728) cap = (unsigned int)((c > 131072) ? 131072 : c);
    }

    const int k3_grid = n / K3_CHUNK;   // 1024

    if (cap) {
        hipMemsetAsync(ws, 0, 4096, stream);   // zero cursor deltas
        k3_scatter<<<k3_grid, K3_THREADS, 0, stream>>>(
            (const float4*)xs, (const float4*)ys, mis, cursors32, keys, cap);
        k4_hist<<<NROWS, 1024, 0, stream>>>(keys, cursors32, (float*)d_out, cap);
        return;
    }

    // ws too small: single-copy atomics directly in d_out, then convert.
    unsigned int* out_u = (unsigned int*)d_out;
    hipMemsetAsync(d_out, 0, (size_t)NXX * NYY * sizeof(float), stream);
    fallback_hist<<<2048, 256, 0, stream>>>(
        (const float4*)xs, (const float4*)ys, mis, out_u, n4);
    convert_kernel<<<(NXX * NYY + 255) / 256, 256, 0, stream>>>(out_u, NXX * NYY);
}